// Round 13
// baseline (255.178 us; speedup 1.0000x reference)
//
#include <hip/hip_runtime.h>
#include <hip/hip_fp16.h>
#include <math.h>

// N = 160000 = 256 * 625; four-step FFT decomposition.
// R27b = R27 resubmission (previous round failed in the container broker, not
// in the kernel). fi AND f1 instrumented (x3 in-kernel repeat, idempotent
// global writes -> bit-identical result). Dual measurement round:
//   top-5 shows fi at 3*t_fi; Dtotal = 2*(t_fi + t_f1) -> t_f1 by subtraction.
// i2 untouched (R26 best: one column/wave, 8 blocks/CU, 2 exact rounds).
// finalize: standalone 1-block.
constexpr int L      = 160000;
constexpr int BATCH  = 8;
constexpr int NB     = 8;
constexpr int NHOPS  = 156;
constexpr int NCHUNK = 155;
constexpr int RS     = 289;   // swizzled row stride (fi)
constexpr float TWO_PI = 6.28318530717958647692f;
constexpr float INVL = 1.0f / (float)L;

__device__ __forceinline__ float2 cmulf(float2 a, float2 b) {
  return make_float2(a.x * b.x - a.y * b.y, a.x * b.y + a.y * b.x);
}

__device__ __forceinline__ float2 cisf(float a) {
  float s, c;
  __sincosf(a, &s, &c);
  return make_float2(c, s);
}

__device__ __forceinline__ float2 conjf(float2 a) { return make_float2(a.x, -a.y); }

__device__ __forceinline__ int pad8(int i) { return i + (i >> 3); }

template <int SIGN>
__device__ __forceinline__ void bf4s(float2* v) {
  float2 t0 = make_float2(v[0].x + v[2].x, v[0].y + v[2].y);
  float2 t1 = make_float2(v[0].x - v[2].x, v[0].y - v[2].y);
  float2 t2 = make_float2(v[1].x + v[3].x, v[1].y + v[3].y);
  float2 t3 = make_float2(v[1].x - v[3].x, v[1].y - v[3].y);
  v[0] = make_float2(t0.x + t2.x, t0.y + t2.y);
  v[2] = make_float2(t0.x - t2.x, t0.y - t2.y);
  if constexpr (SIGN < 0) {
    v[1] = make_float2(t1.x + t3.y, t1.y - t3.x);
    v[3] = make_float2(t1.x - t3.y, t1.y + t3.x);
  } else {
    v[1] = make_float2(t1.x - t3.y, t1.y + t3.x);
    v[3] = make_float2(t1.x + t3.y, t1.y - t3.x);
  }
}

template <int SIGN>
__device__ __forceinline__ void bf5s(float2* v) {
  const float c1 = 0.30901699437494745f, s1 = 0.9510565162951535f;
  const float c2 = -0.8090169943749475f, s2 = 0.5877852522924731f;
  float2 t1 = make_float2(v[1].x + v[4].x, v[1].y + v[4].y);
  float2 t3 = make_float2(v[1].x - v[4].x, v[1].y - v[4].y);
  float2 t2 = make_float2(v[2].x + v[3].x, v[2].y + v[3].y);
  float2 t4 = make_float2(v[2].x - v[3].x, v[2].y - v[3].y);
  float2 a = make_float2(v[0].x + c1 * t1.x + c2 * t2.x, v[0].y + c1 * t1.y + c2 * t2.y);
  float2 b = make_float2(s1 * t3.x + s2 * t4.x, s1 * t3.y + s2 * t4.y);
  float2 c = make_float2(v[0].x + c2 * t1.x + c1 * t2.x, v[0].y + c2 * t1.y + c1 * t2.y);
  float2 d = make_float2(s2 * t3.x - s1 * t4.x, s2 * t3.y - s1 * t4.y);
  v[0] = make_float2(v[0].x + t1.x + t2.x, v[0].y + t1.y + t2.y);
  if constexpr (SIGN < 0) {
    v[1] = make_float2(a.x + b.y, a.y - b.x);
    v[4] = make_float2(a.x - b.y, a.y + b.x);
    v[2] = make_float2(c.x + d.y, c.y - d.x);
    v[3] = make_float2(c.x - d.y, c.y + d.x);
  } else {
    v[1] = make_float2(a.x - b.y, a.y + b.x);
    v[4] = make_float2(a.x + b.y, a.y - b.x);
    v[2] = make_float2(c.x - d.y, c.y + d.x);
    v[3] = make_float2(c.x + d.y, c.y - d.x);
  }
}

template <int R>
__device__ __forceinline__ void twchain(float2* v, float2 t1) {
  float2 t = t1;
  v[1] = cmulf(v[1], t);
#pragma unroll
  for (int r = 2; r < R; ++r) { t = cmulf(t, t1); v[r] = cmulf(v[r], t); }
}

__device__ __forceinline__ int rev3_5(int q) {
  int q5 = q / 5, q25 = q / 25;
  int d0 = q - 5 * q5, d1 = q5 - 5 * q25;
  return 25 * d0 + 5 * d1 + q25;
}

__device__ __forceinline__ int rev3_4(int q) {
  return ((q & 3) << 4) | (q & 12) | (q >> 4);
}

// ---------- single-butterfly DIF-625 stage (128 lanes/column, f1) ----------
template <int SUB, int SIGN>
__device__ __forceinline__ void dif5_stage_1b(float2* a, int idx) {
  int j = idx % SUB;
  int b = (idx / SUB) * (5 * SUB) + j;
  float2 u[5];
#pragma unroll
  for (int r = 0; r < 5; ++r) u[r] = a[b + SUB * r];
  bf5s<SIGN>(u);
  twchain<5>(u, cisf((float)SIGN * (TWO_PI / (float)(5 * SUB)) * (float)j));
#pragma unroll
  for (int r = 0; r < 5; ++r) a[b + SUB * r] = u[r];
}

// ---------- dual-butterfly DIF-625 stage, precomputed twiddles (i2) ----------
template <int SUB>
__device__ __forceinline__ void dif5_ip_stage_t(float2* a, int ln, float2 t1a, float2 t1b) {
  int i1 = ln, i2 = ln + 64;
  bool g2 = (i2 < 125);
  int j1 = i1 % SUB, j2 = i2 % SUB;
  int b1 = (i1 / SUB) * (5 * SUB) + j1;
  int b2 = (i2 / SUB) * (5 * SUB) + j2;
  float2 u[5], v[5];
#pragma unroll
  for (int r = 0; r < 5; ++r) u[r] = a[b1 + SUB * r];
  if (g2) {
#pragma unroll
    for (int r = 0; r < 5; ++r) v[r] = a[b2 + SUB * r];
  }
  bf5s<1>(u);
  twchain<5>(u, t1a);
  if (g2) {
    bf5s<1>(v);
    twchain<5>(v, t1b);
  }
#pragma unroll
  for (int r = 0; r < 5; ++r) a[b1 + SUB * r] = u[r];
  if (g2) {
#pragma unroll
    for (int r = 0; r < 5; ++r) a[b2 + SUB * r] = v[r];
  }
}

// ---------- in-place DIF-256, pad8-swizzled, hoisted twiddles (fi) ----------
template <int SIGN>
__device__ __forceinline__ void dif256sw_tw(float2* a, int ln,
                                            float2 tw1, float2 tw2, float2 tw3) {
  {
    int b = pad8(ln);            // + 72*r exact
    float2 u[4];
#pragma unroll
    for (int r = 0; r < 4; ++r) u[r] = a[b + 72 * r];
    bf4s<SIGN>(u);
    twchain<4>(u, tw1);
#pragma unroll
    for (int r = 0; r < 4; ++r) a[b + 72 * r] = u[r];
  }
  {
    int j = ln & 15, b = pad8(64 * (ln >> 4) + j);   // + 18*r exact
    float2 u[4];
#pragma unroll
    for (int r = 0; r < 4; ++r) u[r] = a[b + 18 * r];
    bf4s<SIGN>(u);
    twchain<4>(u, tw2);
#pragma unroll
    for (int r = 0; r < 4; ++r) a[b + 18 * r] = u[r];
  }
  {
    int j = ln & 3, jb = 16 * (ln >> 2) + j;
    float2 u[4];
#pragma unroll
    for (int r = 0; r < 4; ++r) u[r] = a[pad8(jb + 4 * r)];
    bf4s<SIGN>(u);
    twchain<4>(u, tw3);
#pragma unroll
    for (int r = 0; r < 4; ++r) a[pad8(jb + 4 * r)] = u[r];
  }
  {
    float2 u[4];
#pragma unroll
    for (int r = 0; r < 4; ++r) u[r] = a[pad8(4 * ln + r)];
    bf4s<SIGN>(u);
    int rv = rev3_4(ln);
#pragma unroll
    for (int r = 0; r < 4; ++r) a[pad8(64 * r + rv)] = u[r];
  }
}

// ---------- F1: float4 pack, 2 waves per 625-column, chained epilogue; zero E.
//              INSTRUMENTED: x3 repeat, idempotent G writes. ----------
__global__ __launch_bounds__(512) void f1_kernel(const float* __restrict__ win,
                                                 const float* __restrict__ oin,
                                                 float2* __restrict__ G,
                                                 float* __restrict__ E) {
  __shared__ float2 A[4 * 625];    // 20 KB
  int blk = blockIdx.x;            // grid = BATCH * 64 = 512
  int tid = threadIdx.x;
  int gid = blk * 512 + tid;
  if (gid < 2 * BATCH * NB * NHOPS) E[gid] = 0.0f;   // idempotent
  int sig = blk >> 6, g = blk & 63;
  int n1base = g * 4;
  const float4* wp4 = (const float4*)(win + (size_t)sig * L);
  const float4* op4 = (const float4*)(oin + (size_t)sig * L);
  int col = tid >> 7, idx = tid & 127;
  float2* a = A + col * 625;
  bool act = (idx < 125);
  int cc = tid & 3, k20 = tid >> 2;   // k20 in [0,128)
  int n1 = n1base + cc;
  float w = -(TWO_PI / (float)L) * (float)n1;

#pragma unroll 1
  for (int rep = 0; rep < 3; ++rep) {
    __syncthreads();   // previous rep's epilogue readers done with A
    for (int r = tid; r < 625; r += 512) {
      float4 wv = wp4[r * 64 + g];
      float4 ov = op4[r * 64 + g];
      A[0 * 625 + r] = make_float2(wv.x, ov.x);
      A[1 * 625 + r] = make_float2(wv.y, ov.y);
      A[2 * 625 + r] = make_float2(wv.z, ov.z);
      A[3 * 625 + r] = make_float2(wv.w, ov.w);
    }
    __syncthreads();
    if (act) dif5_stage_1b<125, -1>(a, idx);
    __syncthreads();
    if (act) dif5_stage_1b<25, -1>(a, idx);
    __syncthreads();
    if (act) dif5_stage_1b<5, -1>(a, idx);
    __syncthreads();
    if (act) {
      float2 u[5];
#pragma unroll
      for (int r = 0; r < 5; ++r) u[r] = a[5 * idx + r];
      bf5s<-1>(u);
      int rv = rev3_5(idx);
#pragma unroll
      for (int r = 0; r < 5; ++r) a[125 * r + rv] = u[r];
    }
    __syncthreads();
    // chained epilogue over 512 threads: cc fixed, k2 steps by 128
    float2 t = cisf(w * (float)k20);
    float2 stp = cisf(w * 128.0f);
    for (int k2 = k20; k2 < 625; k2 += 128) {
      G[(size_t)sig * L + k2 * 256 + n1] = cmulf(A[cc * 625 + k2], t);
      t = cmulf(t, stp);
    }
  }
}

// ---------- FI: fused f2+i1, 16 rows / 1024 thr / 2 bands per block (grid 1280).
//              INSTRUMENTED: x3 repeat, idempotent H writes. ----------
__global__ __launch_bounds__(1024) void fi_kernel(const float2* __restrict__ G,
                                                  __half2* __restrict__ H) {
  __shared__ float2 Xb[16 * RS];   // forward spectra (pad8)
  __shared__ float2 Wb[16 * RS];   // inverse work (stages 1-3)
  int blk = blockIdx.x;            // grid = 4 * BATCH * 40 = 1280
  int bg  = blk / (BATCH * 40);    // band-group 0..3 (2 bands each)
  int rem = blk - bg * (BATCH * 40);
  int sig = rem / 40, gr = rem % 40;
  int k2base = gr * 16;
  int tid = threadIdx.x;
  int wv = tid >> 6, ln = tid & 63;
  int k2 = k2base + wv;
  bool act = (k2 < 625);
  float2* xr = Xb + wv * RS;
  float2* wr = Wb + wv * RS;

  // ---- hoisted stage twiddles (inverse sign; forward uses conj) ----
  float2 tw1 = cisf((TWO_PI / 256.0f) * (float)ln);
  float2 tw2 = cisf((TWO_PI / 64.0f) * (float)(ln & 15));
  float2 tw3 = cisf((TWO_PI / 16.0f) * (float)(ln & 3));

  // ---- hoisted per-lane LDS bases (stage strides are exact in pad8 space) ----
  int b1 = pad8(ln);                              // + 72*r
  int b2 = pad8(64 * (ln >> 4) + (ln & 15));      // + 18*r
  int jb3 = 16 * (ln >> 2) + (ln & 3);            // pad8(jb3 + 4*r)
  int kb = 625 * ln + k2;                         // + 40000*r  (bin number)

  // ---- fused stage-4 + epilogue constants ----
  int cc = tid & 15, q = tid >> 4;                // q in 0..63 (butterfly id)
  int rq = rev3_4(q);                             // n1 = 64*r + rq
  int k2e = k2base + cc;
  bool eact = (k2e < 625);
  float a0 = (TWO_PI / (float)L) * (float)k2e;
  float2 t0q = cisf(a0 * (float)rq);
  float2 stp = cisf(a0 * 64.0f);

#pragma unroll 1
  for (int rep = 0; rep < 3; ++rep) {
    __syncthreads();   // previous rep fully done with Xb/Wb
    // ---- forward DIF-256 of own row ----
    if (act) {
#pragma unroll
      for (int r = 0; r < 4; ++r)
        xr[pad8(ln + 64 * r)] = G[(size_t)sig * L + k2 * 256 + ln + 64 * r];
      dif256sw_tw<-1>(xr, ln, conjf(tw1), conjf(tw2), conjf(tw3));
    }

#pragma unroll
    for (int bi = 0; bi < 2; ++bi) {
      int band = bg * 2 + bi;
      unsigned lo1, d1, lo2, d2;
      if (band < 7) {
        lo1 = 10000u * band + 1u;              d1 = 9999u;
        lo2 = (unsigned)L - 10000u * (band + 1); d2 = 9999u;
      } else {
        lo1 = 70001u; d1 = 19998u;             // 70001..89999
        lo2 = 0u;     d2 = 0u;                 // DC bin -> band 7
      }
      if (act) {
        float2 u[4];
        // stage 1: read Xb with in-register band mask, write Wb
#pragma unroll
        for (int r = 0; r < 4; ++r) {
          float2 x = xr[b1 + 72 * r];
          unsigned k = (unsigned)(kb + 40000 * r);
          bool in = ((k - lo1) <= d1) || ((k - lo2) <= d2);
          u[r] = in ? x : make_float2(0.0f, 0.0f);
        }
        bf4s<1>(u);
        twchain<4>(u, tw1);
#pragma unroll
        for (int r = 0; r < 4; ++r) wr[b1 + 72 * r] = u[r];
        // stage 2
#pragma unroll
        for (int r = 0; r < 4; ++r) u[r] = wr[b2 + 18 * r];
        bf4s<1>(u);
        twchain<4>(u, tw2);
#pragma unroll
        for (int r = 0; r < 4; ++r) wr[b2 + 18 * r] = u[r];
        // stage 3
#pragma unroll
        for (int r = 0; r < 4; ++r) u[r] = wr[pad8(jb3 + 4 * r)];
        bf4s<1>(u);
        twchain<4>(u, tw3);
#pragma unroll
        for (int r = 0; r < 4; ++r) wr[pad8(jb3 + 4 * r)] = u[r];
      }
      __syncthreads();
      // fused stage 4 + epilogue: butterfly q of row cc, outputs n1 = 64r + rq
      if (eact) {
        size_t obase = (size_t)(sig * NB + band) * L;
        int b4 = cc * RS + pad8(4 * q);             // + r exact (r<4)
        float2 v[4];
#pragma unroll
        for (int r = 0; r < 4; ++r) v[r] = Wb[b4 + r];
        bf4s<1>(v);
        float2 t = t0q;
#pragma unroll
        for (int r = 0; r < 4; ++r) {
          int n1 = 64 * r + rq;
          float2 val = cmulf(v[r], t);
          H[obase + (size_t)n1 * 625 + k2e] = __floats2half2_rn(val.x * INVL, val.y * INVL);
          t = cmulf(t, stp);
        }
      }
      __syncthreads();
    }
  }
}

// ---------- I2: ONE column per wave, 4 columns / 256-thr block, grid 4096.
//              LDS exactly 20000 B -> 8 blocks/CU = 32 waves/CU, 2 exact
//              rounds. Energy in registers, partials spilled into dead A. ----------
__global__ __launch_bounds__(256, 8) void i2_kernel(const __half2* __restrict__ H,
                                                    float* __restrict__ E) {
  __shared__ float2 A[4 * 625];       // 20000 B (one column per wave)
  int blk = blockIdx.x;               // grid = BATCH*NB*64 = 4096
  int g = blk & 63, sb = blk >> 6;
  int band = sb & 7, sig = sb >> 3;
  int tid = threadIdx.x;
  int wv = tid >> 6, ln = tid & 63;
  size_t base = (size_t)(sig * NB + band) * L;
  int n1 = 4 * g + wv;                // covers 0..255 across 64 blocks x 4 waves
  const __half2* Hc = H + base + (size_t)n1 * 625;
  int j1 = ln, j2 = ln + 64;
  bool g2 = (j2 < 125);
  __half2 h1[5], h2[5];
#pragma unroll
  for (int r = 0; r < 5; ++r) h1[r] = Hc[j1 + 125 * r];
  if (g2) {
#pragma unroll
    for (int r = 0; r < 5; ++r) h2[r] = Hc[j2 + 125 * r];
  }
  float2 tS1a = cisf((TWO_PI / 625.0f) * (float)j1);
  float2 tS1b = cisf((TWO_PI / 625.0f) * (float)j2);
  float2 tS2a = cisf((TWO_PI / 125.0f) * (float)(j1 % 25));
  float2 tS2b = cisf((TWO_PI / 125.0f) * (float)(j2 % 25));
  float2 tS3a = cisf((TWO_PI / 25.0f) * (float)(j1 % 5));
  float2 tS3b = cisf((TWO_PI / 25.0f) * (float)(j2 % 5));
  float2* a = A + wv * 625;

  // ---- stage 1 (from registers) ----
  {
    float2 u[5];
#pragma unroll
    for (int r = 0; r < 5; ++r) u[r] = __half22float2(h1[r]);
    bf5s<1>(u);
    twchain<5>(u, tS1a);
#pragma unroll
    for (int r = 0; r < 5; ++r) a[j1 + 125 * r] = u[r];
    if (g2) {
      float2 v[5];
#pragma unroll
      for (int r = 0; r < 5; ++r) v[r] = __half22float2(h2[r]);
      bf5s<1>(v);
      twchain<5>(v, tS1b);
#pragma unroll
      for (int r = 0; r < 5; ++r) a[j2 + 125 * r] = v[r];
    }
  }
  // ---- stages 2-3 ----
  dif5_ip_stage_t<25>(a, ln, tS2a, tS2b);
  dif5_ip_stage_t<5>(a, ln, tS3a, tS3b);
  // ---- final stage ----
  {
    float2 u[5], v[5];
#pragma unroll
    for (int r = 0; r < 5; ++r) u[r] = a[5 * j1 + r];
    if (g2) {
#pragma unroll
      for (int r = 0; r < 5; ++r) v[r] = a[5 * j2 + r];
    }
    bf5s<1>(u);
    if (g2) bf5s<1>(v);
    int rv1 = rev3_5(j1), rv2 = rev3_5(j2);
#pragma unroll
    for (int r = 0; r < 5; ++r) a[125 * r + rv1] = u[r];
    if (g2) {
#pragma unroll
      for (int r = 0; r < 5; ++r) a[125 * r + rv2] = v[r];
    }
  }
  // ---- energy pass into registers ----
  float ex[3] = {0.0f, 0.0f, 0.0f}, ey[3] = {0.0f, 0.0f, 0.0f};
#pragma unroll
  for (int k = 0; k < 3; ++k) {
    int h = ln + 64 * k;
    if (h < NHOPS) {
#pragma unroll
      for (int d = 0; d < 4; ++d) {
        float2 z = a[4 * h + d];
        ex[k] += z.x * z.x;
        ey[k] += z.y * z.y;
      }
    }
  }
  __syncthreads();                       // all waves done with A
  float* Ps = (float*)A;                 // 4 waves x 312 floats = 4992 B scratch
#pragma unroll
  for (int k = 0; k < 3; ++k) {
    int h = ln + 64 * k;
    if (h < NHOPS) {
      Ps[wv * (2 * NHOPS) + h] = ex[k];
      Ps[wv * (2 * NHOPS) + NHOPS + h] = ey[k];
    }
  }
  __syncthreads();
  int eb = (sig * NB + band) * NHOPS;
  for (int idx = tid; idx < 2 * NHOPS; idx += 256) {
    float v = Ps[idx] + Ps[2 * NHOPS + idx] + Ps[4 * NHOPS + idx] + Ps[6 * NHOPS + idx];
    int comp = idx / NHOPS, h = idx - comp * NHOPS;
    atomicAdd(&E[comp * (BATCH * NB * NHOPS) + eb + h], v);
  }
}

// ---------- finalize: loudness, diff, softmax (H pre-scaled by 1/L -> SC = 1/2048) ----------
__global__ __launch_bounds__(1024) void finalize_kernel(const float* __restrict__ E,
                                                        float* __restrict__ out) {
  constexpr int ND = BATCH * NB * NCHUNK;  // 9920
  constexpr float SC = 1.0f / 2048.0f;
  __shared__ float diffs[ND];
  __shared__ float sred[1024];
  int tid = threadIdx.x;
  for (int idx = tid; idx < ND; idx += 1024) {
    int sb = idx / NCHUNK;
    int k = idx - sb * NCHUNK;
    float msw = (E[sb * NHOPS + k] + E[sb * NHOPS + k + 1]) * SC;
    float mso = (E[64 * NHOPS + sb * NHOPS + k] + E[64 * NHOPS + sb * NHOPS + k + 1]) * SC;
    float lw = -0.691f + 10.0f * log10f(msw + 1e-12f);
    float lo = -0.691f + 10.0f * log10f(mso + 1e-12f);
    diffs[idx] = lw - lo;
  }
  __syncthreads();
  float mx = -3.4e38f;
  for (int idx = tid; idx < ND; idx += 1024) mx = fmaxf(mx, diffs[idx]);
  sred[tid] = mx;
  __syncthreads();
  for (int s = 512; s > 0; s >>= 1) {
    if (tid < s) sred[tid] = fmaxf(sred[tid], sred[tid + s]);
    __syncthreads();
  }
  float gmax = sred[0];
  __syncthreads();
  float se = 0.0f, swd = 0.0f;
  for (int idx = tid; idx < ND; idx += 1024) {
    float d = diffs[idx];
    float e = expf(d - gmax);
    se += e;
    swd += d * e;
  }
  sred[tid] = se; __syncthreads();
  for (int s = 512; s > 0; s >>= 1) { if (tid < s) sred[tid] += sred[tid + s]; __syncthreads(); }
  float tot = sred[0];
  __syncthreads();
  sred[tid] = swd; __syncthreads();
  for (int s = 512; s > 0; s >>= 1) { if (tid < s) sred[tid] += sred[tid + s]; __syncthreads(); }
  if (tid == 0) out[0] = sred[0] / tot;
}

extern "C" void kernel_launch(void* const* d_in, const int* in_sizes, int n_in,
                              void* d_out, int out_size, void* d_ws, size_t ws_size,
                              hipStream_t stream) {
  (void)in_sizes; (void)n_in; (void)out_size; (void)ws_size;
  char* ws = (char*)d_ws;
  float2*  G = (float2*)ws;                        // 10,240,000 B
  __half2* H = (__half2*)(ws + 10240000);          // 40,960,000 B (fp16)
  float*   E = (float*)(ws + 51200000);            // 79,872 B [2][64][156]
  const float* w = (const float*)d_in[0];
  const float* o = (const float*)d_in[1];

  f1_kernel<<<dim3(BATCH * 64), dim3(512), 0, stream>>>(w, o, G, E);
  fi_kernel<<<dim3(4 * BATCH * 40), dim3(1024), 0, stream>>>(G, H);
  i2_kernel<<<dim3(BATCH * NB * 64), dim3(256), 0, stream>>>(H, E);
  finalize_kernel<<<dim3(1), dim3(1024), 0, stream>>>(E, (float*)d_out);
}

// Round 14
// 146.193 us; speedup vs baseline: 1.7455x; 1.7455x over previous
//
#include <hip/hip_runtime.h>
#include <hip/hip_fp16.h>
#include <math.h>

// N = 160000 = 256 * 625; four-step FFT decomposition.
// R28 = R26 (instrumentation reverted) + two fi fixes from the R27 measurement
// (t_fi=40.6, t_f1=15.9, i2=41, fill=44.5 -> budget closes exactly):
//  1. fi forward stage-1 computed IN REGISTERS (lane ln loads G[ln+64r] which
//     are exactly its stage-1 inputs) -> deletes one full LDS round-trip and
//     shortens the serial chain. Stages 2-4 via dif256sw_s234.
//  2. H rows padded 625 -> 640 half2 (2560 B, 64-aligned; k2base*4 = 64 B)
//     -> fi's 64B store groups no longer split cache lines (measured 1.38x
//     write amplification -> 1.0x). i2 reads use the same stride.
// f1: pack w+i*o (float4), 2 waves per 625-column, chained epilogue; zeroes E.
// fi: fused f2+i1, 16 rows / 1024 thr / 2 bands per block (grid 1280).
// i2: one column/wave, 4 cols / 256-thr block, 8 blocks/CU, 2 exact rounds.
// finalize: standalone 1-block (fused variant hit cross-XCD fence cost, R21).
constexpr int L      = 160000;
constexpr int BATCH  = 8;
constexpr int NB     = 8;
constexpr int NHOPS  = 156;
constexpr int NCHUNK = 155;
constexpr int RS     = 289;     // swizzled row stride (fi)
constexpr int HP     = 640;     // padded H row stride (half2), 64B-aligned
constexpr int HL     = 256 * HP; // per-(sig,band) H extent
constexpr float TWO_PI = 6.28318530717958647692f;
constexpr float INVL = 1.0f / (float)L;

__device__ __forceinline__ float2 cmulf(float2 a, float2 b) {
  return make_float2(a.x * b.x - a.y * b.y, a.x * b.y + a.y * b.x);
}

__device__ __forceinline__ float2 cisf(float a) {
  float s, c;
  __sincosf(a, &s, &c);
  return make_float2(c, s);
}

__device__ __forceinline__ float2 conjf(float2 a) { return make_float2(a.x, -a.y); }

__device__ __forceinline__ int pad8(int i) { return i + (i >> 3); }

template <int SIGN>
__device__ __forceinline__ void bf4s(float2* v) {
  float2 t0 = make_float2(v[0].x + v[2].x, v[0].y + v[2].y);
  float2 t1 = make_float2(v[0].x - v[2].x, v[0].y - v[2].y);
  float2 t2 = make_float2(v[1].x + v[3].x, v[1].y + v[3].y);
  float2 t3 = make_float2(v[1].x - v[3].x, v[1].y - v[3].y);
  v[0] = make_float2(t0.x + t2.x, t0.y + t2.y);
  v[2] = make_float2(t0.x - t2.x, t0.y - t2.y);
  if constexpr (SIGN < 0) {
    v[1] = make_float2(t1.x + t3.y, t1.y - t3.x);
    v[3] = make_float2(t1.x - t3.y, t1.y + t3.x);
  } else {
    v[1] = make_float2(t1.x - t3.y, t1.y + t3.x);
    v[3] = make_float2(t1.x + t3.y, t1.y - t3.x);
  }
}

template <int SIGN>
__device__ __forceinline__ void bf5s(float2* v) {
  const float c1 = 0.30901699437494745f, s1 = 0.9510565162951535f;
  const float c2 = -0.8090169943749475f, s2 = 0.5877852522924731f;
  float2 t1 = make_float2(v[1].x + v[4].x, v[1].y + v[4].y);
  float2 t3 = make_float2(v[1].x - v[4].x, v[1].y - v[4].y);
  float2 t2 = make_float2(v[2].x + v[3].x, v[2].y + v[3].y);
  float2 t4 = make_float2(v[2].x - v[3].x, v[2].y - v[3].y);
  float2 a = make_float2(v[0].x + c1 * t1.x + c2 * t2.x, v[0].y + c1 * t1.y + c2 * t2.y);
  float2 b = make_float2(s1 * t3.x + s2 * t4.x, s1 * t3.y + s2 * t4.y);
  float2 c = make_float2(v[0].x + c2 * t1.x + c1 * t2.x, v[0].y + c2 * t1.y + c1 * t2.y);
  float2 d = make_float2(s2 * t3.x - s1 * t4.x, s2 * t3.y - s1 * t4.y);
  v[0] = make_float2(v[0].x + t1.x + t2.x, v[0].y + t1.y + t2.y);
  if constexpr (SIGN < 0) {
    v[1] = make_float2(a.x + b.y, a.y - b.x);
    v[4] = make_float2(a.x - b.y, a.y + b.x);
    v[2] = make_float2(c.x + d.y, c.y - d.x);
    v[3] = make_float2(c.x - d.y, c.y + d.x);
  } else {
    v[1] = make_float2(a.x - b.y, a.y + b.x);
    v[4] = make_float2(a.x + b.y, a.y - b.x);
    v[2] = make_float2(c.x - d.y, c.y + d.x);
    v[3] = make_float2(c.x + d.y, c.y - d.x);
  }
}

template <int R>
__device__ __forceinline__ void twchain(float2* v, float2 t1) {
  float2 t = t1;
  v[1] = cmulf(v[1], t);
#pragma unroll
  for (int r = 2; r < R; ++r) { t = cmulf(t, t1); v[r] = cmulf(v[r], t); }
}

__device__ __forceinline__ int rev3_5(int q) {
  int q5 = q / 5, q25 = q / 25;
  int d0 = q - 5 * q5, d1 = q5 - 5 * q25;
  return 25 * d0 + 5 * d1 + q25;
}

__device__ __forceinline__ int rev3_4(int q) {
  return ((q & 3) << 4) | (q & 12) | (q >> 4);
}

// ---------- single-butterfly DIF-625 stage (128 lanes/column, f1) ----------
template <int SUB, int SIGN>
__device__ __forceinline__ void dif5_stage_1b(float2* a, int idx) {
  int j = idx % SUB;
  int b = (idx / SUB) * (5 * SUB) + j;
  float2 u[5];
#pragma unroll
  for (int r = 0; r < 5; ++r) u[r] = a[b + SUB * r];
  bf5s<SIGN>(u);
  twchain<5>(u, cisf((float)SIGN * (TWO_PI / (float)(5 * SUB)) * (float)j));
#pragma unroll
  for (int r = 0; r < 5; ++r) a[b + SUB * r] = u[r];
}

// ---------- dual-butterfly DIF-625 stage, precomputed twiddles (i2) ----------
template <int SUB>
__device__ __forceinline__ void dif5_ip_stage_t(float2* a, int ln, float2 t1a, float2 t1b) {
  int i1 = ln, i2 = ln + 64;
  bool g2 = (i2 < 125);
  int j1 = i1 % SUB, j2 = i2 % SUB;
  int b1 = (i1 / SUB) * (5 * SUB) + j1;
  int b2 = (i2 / SUB) * (5 * SUB) + j2;
  float2 u[5], v[5];
#pragma unroll
  for (int r = 0; r < 5; ++r) u[r] = a[b1 + SUB * r];
  if (g2) {
#pragma unroll
    for (int r = 0; r < 5; ++r) v[r] = a[b2 + SUB * r];
  }
  bf5s<1>(u);
  twchain<5>(u, t1a);
  if (g2) {
    bf5s<1>(v);
    twchain<5>(v, t1b);
  }
#pragma unroll
  for (int r = 0; r < 5; ++r) a[b1 + SUB * r] = u[r];
  if (g2) {
#pragma unroll
    for (int r = 0; r < 5; ++r) a[b2 + SUB * r] = v[r];
  }
}

// ---------- DIF-256 stages 2-4 only, pad8-swizzled, hoisted twiddles (fi fwd) ----------
template <int SIGN>
__device__ __forceinline__ void dif256sw_s234(float2* a, int ln, float2 tw2, float2 tw3) {
  {
    int j = ln & 15, b = pad8(64 * (ln >> 4) + j);   // + 18*r exact
    float2 u[4];
#pragma unroll
    for (int r = 0; r < 4; ++r) u[r] = a[b + 18 * r];
    bf4s<SIGN>(u);
    twchain<4>(u, tw2);
#pragma unroll
    for (int r = 0; r < 4; ++r) a[b + 18 * r] = u[r];
  }
  {
    int j = ln & 3, jb = 16 * (ln >> 2) + j;
    float2 u[4];
#pragma unroll
    for (int r = 0; r < 4; ++r) u[r] = a[pad8(jb + 4 * r)];
    bf4s<SIGN>(u);
    twchain<4>(u, tw3);
#pragma unroll
    for (int r = 0; r < 4; ++r) a[pad8(jb + 4 * r)] = u[r];
  }
  {
    float2 u[4];
#pragma unroll
    for (int r = 0; r < 4; ++r) u[r] = a[pad8(4 * ln + r)];
    bf4s<SIGN>(u);
    int rv = rev3_4(ln);
#pragma unroll
    for (int r = 0; r < 4; ++r) a[pad8(64 * r + rv)] = u[r];
  }
}

// ---------- F1: float4 pack, 2 waves per 625-column, chained epilogue; zero E ----------
__global__ __launch_bounds__(512) void f1_kernel(const float* __restrict__ win,
                                                 const float* __restrict__ oin,
                                                 float2* __restrict__ G,
                                                 float* __restrict__ E) {
  __shared__ float2 A[4 * 625];    // 20 KB
  int blk = blockIdx.x;            // grid = BATCH * 64 = 512
  int tid = threadIdx.x;
  int gid = blk * 512 + tid;
  if (gid < 2 * BATCH * NB * NHOPS) E[gid] = 0.0f;   // replaces memset launch
  int sig = blk >> 6, g = blk & 63;
  int n1base = g * 4;
  const float4* wp4 = (const float4*)(win + (size_t)sig * L);
  const float4* op4 = (const float4*)(oin + (size_t)sig * L);
  for (int r = tid; r < 625; r += 512) {
    float4 wv = wp4[r * 64 + g];
    float4 ov = op4[r * 64 + g];
    A[0 * 625 + r] = make_float2(wv.x, ov.x);
    A[1 * 625 + r] = make_float2(wv.y, ov.y);
    A[2 * 625 + r] = make_float2(wv.z, ov.z);
    A[3 * 625 + r] = make_float2(wv.w, ov.w);
  }
  __syncthreads();
  // 2 waves per column: 128 lanes, 1 butterfly each (125 active)
  int col = tid >> 7, idx = tid & 127;
  float2* a = A + col * 625;
  bool act = (idx < 125);
  if (act) dif5_stage_1b<125, -1>(a, idx);
  __syncthreads();
  if (act) dif5_stage_1b<25, -1>(a, idx);
  __syncthreads();
  if (act) dif5_stage_1b<5, -1>(a, idx);
  __syncthreads();
  if (act) {
    float2 u[5];
#pragma unroll
    for (int r = 0; r < 5; ++r) u[r] = a[5 * idx + r];
    bf5s<-1>(u);
    int rv = rev3_5(idx);
#pragma unroll
    for (int r = 0; r < 5; ++r) a[125 * r + rv] = u[r];
  }
  __syncthreads();
  // chained epilogue over 512 threads: cc fixed, k2 steps by 128
  int cc = tid & 3, k20 = tid >> 2;   // k20 in [0,128)
  int n1 = n1base + cc;
  float w = -(TWO_PI / (float)L) * (float)n1;
  float2 t = cisf(w * (float)k20);
  float2 stp = cisf(w * 128.0f);
  for (int k2 = k20; k2 < 625; k2 += 128) {
    G[(size_t)sig * L + k2 * 256 + n1] = cmulf(A[cc * 625 + k2], t);
    t = cmulf(t, stp);
  }
}

// ---------- FI: fused f2+i1, 16 rows / 1024 thr / 2 bands per block (grid 1280).
//              Forward stage-1 in registers; aligned (HP=640) H writes. ----------
__global__ __launch_bounds__(1024) void fi_kernel(const float2* __restrict__ G,
                                                  __half2* __restrict__ H) {
  __shared__ float2 Xb[16 * RS];   // forward spectra (pad8)
  __shared__ float2 Wb[16 * RS];   // inverse work (stages 1-3)
  int blk = blockIdx.x;            // grid = 4 * BATCH * 40 = 1280
  int bg  = blk / (BATCH * 40);    // band-group 0..3 (2 bands each)
  int rem = blk - bg * (BATCH * 40);
  int sig = rem / 40, gr = rem % 40;
  int k2base = gr * 16;
  int tid = threadIdx.x;
  int wv = tid >> 6, ln = tid & 63;
  int k2 = k2base + wv;
  bool act = (k2 < 625);
  float2* xr = Xb + wv * RS;
  float2* wr = Wb + wv * RS;

  // ---- hoisted stage twiddles (inverse sign; forward uses conj) ----
  float2 tw1 = cisf((TWO_PI / 256.0f) * (float)ln);
  float2 tw2 = cisf((TWO_PI / 64.0f) * (float)(ln & 15));
  float2 tw3 = cisf((TWO_PI / 16.0f) * (float)(ln & 3));

  // ---- forward DIF-256 of own row: stage 1 in registers (lane ln's G loads
  //      ARE its stage-1 inputs), stages 2-4 through LDS ----
  if (act) {
    const float2* Gr = G + (size_t)sig * L + k2 * 256;
    float2 x[4];
#pragma unroll
    for (int r = 0; r < 4; ++r) x[r] = Gr[ln + 64 * r];
    bf4s<-1>(x);
    twchain<4>(x, conjf(tw1));
    int b1w = pad8(ln);                           // + 72*r exact
#pragma unroll
    for (int r = 0; r < 4; ++r) xr[b1w + 72 * r] = x[r];
    dif256sw_s234<-1>(xr, ln, conjf(tw2), conjf(tw3));
  }

  // ---- hoisted per-lane LDS bases (stage strides are exact in pad8 space) ----
  int b1 = pad8(ln);                              // + 72*r
  int b2 = pad8(64 * (ln >> 4) + (ln & 15));      // + 18*r
  int jb3 = 16 * (ln >> 2) + (ln & 3);            // pad8(jb3 + 4*r)
  int kb = 625 * ln + k2;                         // + 40000*r  (bin number)

  // ---- fused stage-4 + epilogue constants ----
  int cc = tid & 15, q = tid >> 4;                // q in 0..63 (butterfly id)
  int rq = rev3_4(q);                             // n1 = 64*r + rq
  int k2e = k2base + cc;
  bool eact = (k2e < 625);
  float a0 = (TWO_PI / (float)L) * (float)k2e;
  float2 t0q = cisf(a0 * (float)rq);
  float2 stp = cisf(a0 * 64.0f);

#pragma unroll
  for (int bi = 0; bi < 2; ++bi) {
    int band = bg * 2 + bi;
    unsigned lo1, d1, lo2, d2;
    if (band < 7) {
      lo1 = 10000u * band + 1u;              d1 = 9999u;
      lo2 = (unsigned)L - 10000u * (band + 1); d2 = 9999u;
    } else {
      lo1 = 70001u; d1 = 19998u;             // 70001..89999
      lo2 = 0u;     d2 = 0u;                 // DC bin -> band 7
    }
    if (act) {
      float2 u[4];
      // stage 1: read Xb with in-register band mask, write Wb
#pragma unroll
      for (int r = 0; r < 4; ++r) {
        float2 x = xr[b1 + 72 * r];
        unsigned k = (unsigned)(kb + 40000 * r);
        bool in = ((k - lo1) <= d1) || ((k - lo2) <= d2);
        u[r] = in ? x : make_float2(0.0f, 0.0f);
      }
      bf4s<1>(u);
      twchain<4>(u, tw1);
#pragma unroll
      for (int r = 0; r < 4; ++r) wr[b1 + 72 * r] = u[r];
      // stage 2
#pragma unroll
      for (int r = 0; r < 4; ++r) u[r] = wr[b2 + 18 * r];
      bf4s<1>(u);
      twchain<4>(u, tw2);
#pragma unroll
      for (int r = 0; r < 4; ++r) wr[b2 + 18 * r] = u[r];
      // stage 3
#pragma unroll
      for (int r = 0; r < 4; ++r) u[r] = wr[pad8(jb3 + 4 * r)];
      bf4s<1>(u);
      twchain<4>(u, tw3);
#pragma unroll
      for (int r = 0; r < 4; ++r) wr[pad8(jb3 + 4 * r)] = u[r];
    }
    __syncthreads();
    // fused stage 4 + epilogue: butterfly q of row cc, outputs n1 = 64r + rq
    if (eact) {
      size_t obase = (size_t)(sig * NB + band) * HL;
      int b4 = cc * RS + pad8(4 * q);             // + r exact (r<4)
      float2 v[4];
#pragma unroll
      for (int r = 0; r < 4; ++r) v[r] = Wb[b4 + r];
      bf4s<1>(v);
      float2 t = t0q;
#pragma unroll
      for (int r = 0; r < 4; ++r) {
        int n1 = 64 * r + rq;
        float2 val = cmulf(v[r], t);
        H[obase + (size_t)n1 * HP + k2e] = __floats2half2_rn(val.x * INVL, val.y * INVL);
        t = cmulf(t, stp);
      }
    }
    __syncthreads();
  }
}

// ---------- I2: ONE column per wave, 4 columns / 256-thr block, grid 4096.
//              LDS exactly 20000 B -> 8 blocks/CU = 32 waves/CU, 2 exact
//              rounds. Energy in registers, partials spilled into dead A. ----------
__global__ __launch_bounds__(256, 8) void i2_kernel(const __half2* __restrict__ H,
                                                    float* __restrict__ E) {
  __shared__ float2 A[4 * 625];       // 20000 B (one column per wave)
  int blk = blockIdx.x;               // grid = BATCH*NB*64 = 4096
  int g = blk & 63, sb = blk >> 6;
  int band = sb & 7, sig = sb >> 3;
  int tid = threadIdx.x;
  int wv = tid >> 6, ln = tid & 63;
  size_t base = (size_t)(sig * NB + band) * HL;
  int n1 = 4 * g + wv;                // covers 0..255 across 64 blocks x 4 waves
  const __half2* Hc = H + base + (size_t)n1 * HP;
  int j1 = ln, j2 = ln + 64;
  bool g2 = (j2 < 125);
  __half2 h1[5], h2[5];
#pragma unroll
  for (int r = 0; r < 5; ++r) h1[r] = Hc[j1 + 125 * r];
  if (g2) {
#pragma unroll
    for (int r = 0; r < 5; ++r) h2[r] = Hc[j2 + 125 * r];
  }
  float2 tS1a = cisf((TWO_PI / 625.0f) * (float)j1);
  float2 tS1b = cisf((TWO_PI / 625.0f) * (float)j2);
  float2 tS2a = cisf((TWO_PI / 125.0f) * (float)(j1 % 25));
  float2 tS2b = cisf((TWO_PI / 125.0f) * (float)(j2 % 25));
  float2 tS3a = cisf((TWO_PI / 25.0f) * (float)(j1 % 5));
  float2 tS3b = cisf((TWO_PI / 25.0f) * (float)(j2 % 5));
  float2* a = A + wv * 625;

  // ---- stage 1 (from registers) ----
  {
    float2 u[5];
#pragma unroll
    for (int r = 0; r < 5; ++r) u[r] = __half22float2(h1[r]);
    bf5s<1>(u);
    twchain<5>(u, tS1a);
#pragma unroll
    for (int r = 0; r < 5; ++r) a[j1 + 125 * r] = u[r];
    if (g2) {
      float2 v[5];
#pragma unroll
      for (int r = 0; r < 5; ++r) v[r] = __half22float2(h2[r]);
      bf5s<1>(v);
      twchain<5>(v, tS1b);
#pragma unroll
      for (int r = 0; r < 5; ++r) a[j2 + 125 * r] = v[r];
    }
  }
  // ---- stages 2-3 ----
  dif5_ip_stage_t<25>(a, ln, tS2a, tS2b);
  dif5_ip_stage_t<5>(a, ln, tS3a, tS3b);
  // ---- final stage ----
  {
    float2 u[5], v[5];
#pragma unroll
    for (int r = 0; r < 5; ++r) u[r] = a[5 * j1 + r];
    if (g2) {
#pragma unroll
      for (int r = 0; r < 5; ++r) v[r] = a[5 * j2 + r];
    }
    bf5s<1>(u);
    if (g2) bf5s<1>(v);
    int rv1 = rev3_5(j1), rv2 = rev3_5(j2);
#pragma unroll
    for (int r = 0; r < 5; ++r) a[125 * r + rv1] = u[r];
    if (g2) {
#pragma unroll
      for (int r = 0; r < 5; ++r) a[125 * r + rv2] = v[r];
    }
  }
  // ---- energy pass into registers ----
  float ex[3] = {0.0f, 0.0f, 0.0f}, ey[3] = {0.0f, 0.0f, 0.0f};
#pragma unroll
  for (int k = 0; k < 3; ++k) {
    int h = ln + 64 * k;
    if (h < NHOPS) {
#pragma unroll
      for (int d = 0; d < 4; ++d) {
        float2 z = a[4 * h + d];
        ex[k] += z.x * z.x;
        ey[k] += z.y * z.y;
      }
    }
  }
  __syncthreads();                       // all waves done with A
  float* Ps = (float*)A;                 // 4 waves x 312 floats = 4992 B scratch
#pragma unroll
  for (int k = 0; k < 3; ++k) {
    int h = ln + 64 * k;
    if (h < NHOPS) {
      Ps[wv * (2 * NHOPS) + h] = ex[k];
      Ps[wv * (2 * NHOPS) + NHOPS + h] = ey[k];
    }
  }
  __syncthreads();
  int eb = (sig * NB + band) * NHOPS;
  for (int idx = tid; idx < 2 * NHOPS; idx += 256) {
    float v = Ps[idx] + Ps[2 * NHOPS + idx] + Ps[4 * NHOPS + idx] + Ps[6 * NHOPS + idx];
    int comp = idx / NHOPS, h = idx - comp * NHOPS;
    atomicAdd(&E[comp * (BATCH * NB * NHOPS) + eb + h], v);
  }
}

// ---------- finalize: loudness, diff, softmax (H pre-scaled by 1/L -> SC = 1/2048) ----------
__global__ __launch_bounds__(1024) void finalize_kernel(const float* __restrict__ E,
                                                        float* __restrict__ out) {
  constexpr int ND = BATCH * NB * NCHUNK;  // 9920
  constexpr float SC = 1.0f / 2048.0f;
  __shared__ float diffs[ND];
  __shared__ float sred[1024];
  int tid = threadIdx.x;
  for (int idx = tid; idx < ND; idx += 1024) {
    int sb = idx / NCHUNK;
    int k = idx - sb * NCHUNK;
    float msw = (E[sb * NHOPS + k] + E[sb * NHOPS + k + 1]) * SC;
    float mso = (E[64 * NHOPS + sb * NHOPS + k] + E[64 * NHOPS + sb * NHOPS + k + 1]) * SC;
    float lw = -0.691f + 10.0f * log10f(msw + 1e-12f);
    float lo = -0.691f + 10.0f * log10f(mso + 1e-12f);
    diffs[idx] = lw - lo;
  }
  __syncthreads();
  float mx = -3.4e38f;
  for (int idx = tid; idx < ND; idx += 1024) mx = fmaxf(mx, diffs[idx]);
  sred[tid] = mx;
  __syncthreads();
  for (int s = 512; s > 0; s >>= 1) {
    if (tid < s) sred[tid] = fmaxf(sred[tid], sred[tid + s]);
    __syncthreads();
  }
  float gmax = sred[0];
  __syncthreads();
  float se = 0.0f, swd = 0.0f;
  for (int idx = tid; idx < ND; idx += 1024) {
    float d = diffs[idx];
    float e = expf(d - gmax);
    se += e;
    swd += d * e;
  }
  sred[tid] = se; __syncthreads();
  for (int s = 512; s > 0; s >>= 1) { if (tid < s) sred[tid] += sred[tid + s]; __syncthreads(); }
  float tot = sred[0];
  __syncthreads();
  sred[tid] = swd; __syncthreads();
  for (int s = 512; s > 0; s >>= 1) { if (tid < s) sred[tid] += sred[tid + s]; __syncthreads(); }
  if (tid == 0) out[0] = sred[0] / tot;
}

extern "C" void kernel_launch(void* const* d_in, const int* in_sizes, int n_in,
                              void* d_out, int out_size, void* d_ws, size_t ws_size,
                              hipStream_t stream) {
  (void)in_sizes; (void)n_in; (void)out_size; (void)ws_size;
  char* ws = (char*)d_ws;
  float2*  G = (float2*)ws;                        // 10,240,000 B
  __half2* H = (__half2*)(ws + 10240000);          // 41,943,040 B (fp16, HP=640)
  float*   E = (float*)(ws + 52183040);            // 79,872 B [2][64][156]
  const float* w = (const float*)d_in[0];
  const float* o = (const float*)d_in[1];

  f1_kernel<<<dim3(BATCH * 64), dim3(512), 0, stream>>>(w, o, G, E);
  fi_kernel<<<dim3(4 * BATCH * 40), dim3(1024), 0, stream>>>(G, H);
  i2_kernel<<<dim3(BATCH * NB * 64), dim3(256), 0, stream>>>(H, E);
  finalize_kernel<<<dim3(1), dim3(1024), 0, stream>>>(E, (float*)d_out);
}

// Round 15
// 140.432 us; speedup vs baseline: 1.8171x; 1.0410x over previous
//
#include <hip/hip_runtime.h>
#include <hip/hip_fp16.h>
#include <math.h>

// N = 160000 = 256 * 625; four-step FFT decomposition.
// R29 = R28 with the H stride fixed: HP=640 (2560 B = 2^9*5) aliased L2/HBM
// channels (n1*2560 mod 4096 hits only 8 offsets) and regressed despite fixing
// line splits. HP=656 (2624 B = 64*41): 64B-aligned rows (no line splits) AND
// odd multiple of 64 -> full channel spread. reg-stage-1 in fi kept (strict
// work removal, addresses verified identical: pad8(ln+64r)=pad8(ln)+72r).
// f1: pack w+i*o (float4), 2 waves per 625-column, chained epilogue; zeroes E.
// fi: fused f2+i1, 16 rows / 1024 thr / 2 bands per block (grid 1280).
// i2: one column/wave, 4 cols / 256-thr block, 8 blocks/CU, 2 exact rounds.
// finalize: standalone 1-block (fused variant hit cross-XCD fence cost, R21).
constexpr int L      = 160000;
constexpr int BATCH  = 8;
constexpr int NB     = 8;
constexpr int NHOPS  = 156;
constexpr int NCHUNK = 155;
constexpr int RS     = 289;      // swizzled row stride (fi)
constexpr int HP     = 656;      // padded H row stride (half2) = 2624 B = 64*41
constexpr int HL     = 256 * HP; // per-(sig,band) H extent
constexpr float TWO_PI = 6.28318530717958647692f;
constexpr float INVL = 1.0f / (float)L;

__device__ __forceinline__ float2 cmulf(float2 a, float2 b) {
  return make_float2(a.x * b.x - a.y * b.y, a.x * b.y + a.y * b.x);
}

__device__ __forceinline__ float2 cisf(float a) {
  float s, c;
  __sincosf(a, &s, &c);
  return make_float2(c, s);
}

__device__ __forceinline__ float2 conjf(float2 a) { return make_float2(a.x, -a.y); }

__device__ __forceinline__ int pad8(int i) { return i + (i >> 3); }

template <int SIGN>
__device__ __forceinline__ void bf4s(float2* v) {
  float2 t0 = make_float2(v[0].x + v[2].x, v[0].y + v[2].y);
  float2 t1 = make_float2(v[0].x - v[2].x, v[0].y - v[2].y);
  float2 t2 = make_float2(v[1].x + v[3].x, v[1].y + v[3].y);
  float2 t3 = make_float2(v[1].x - v[3].x, v[1].y - v[3].y);
  v[0] = make_float2(t0.x + t2.x, t0.y + t2.y);
  v[2] = make_float2(t0.x - t2.x, t0.y - t2.y);
  if constexpr (SIGN < 0) {
    v[1] = make_float2(t1.x + t3.y, t1.y - t3.x);
    v[3] = make_float2(t1.x - t3.y, t1.y + t3.x);
  } else {
    v[1] = make_float2(t1.x - t3.y, t1.y + t3.x);
    v[3] = make_float2(t1.x + t3.y, t1.y - t3.x);
  }
}

template <int SIGN>
__device__ __forceinline__ void bf5s(float2* v) {
  const float c1 = 0.30901699437494745f, s1 = 0.9510565162951535f;
  const float c2 = -0.8090169943749475f, s2 = 0.5877852522924731f;
  float2 t1 = make_float2(v[1].x + v[4].x, v[1].y + v[4].y);
  float2 t3 = make_float2(v[1].x - v[4].x, v[1].y - v[4].y);
  float2 t2 = make_float2(v[2].x + v[3].x, v[2].y + v[3].y);
  float2 t4 = make_float2(v[2].x - v[3].x, v[2].y - v[3].y);
  float2 a = make_float2(v[0].x + c1 * t1.x + c2 * t2.x, v[0].y + c1 * t1.y + c2 * t2.y);
  float2 b = make_float2(s1 * t3.x + s2 * t4.x, s1 * t3.y + s2 * t4.y);
  float2 c = make_float2(v[0].x + c2 * t1.x + c1 * t2.x, v[0].y + c2 * t1.y + c1 * t2.y);
  float2 d = make_float2(s2 * t3.x - s1 * t4.x, s2 * t3.y - s1 * t4.y);
  v[0] = make_float2(v[0].x + t1.x + t2.x, v[0].y + t1.y + t2.y);
  if constexpr (SIGN < 0) {
    v[1] = make_float2(a.x + b.y, a.y - b.x);
    v[4] = make_float2(a.x - b.y, a.y + b.x);
    v[2] = make_float2(c.x + d.y, c.y - d.x);
    v[3] = make_float2(c.x - d.y, c.y + d.x);
  } else {
    v[1] = make_float2(a.x - b.y, a.y + b.x);
    v[4] = make_float2(a.x + b.y, a.y - b.x);
    v[2] = make_float2(c.x - d.y, c.y + d.x);
    v[3] = make_float2(c.x + d.y, c.y - d.x);
  }
}

template <int R>
__device__ __forceinline__ void twchain(float2* v, float2 t1) {
  float2 t = t1;
  v[1] = cmulf(v[1], t);
#pragma unroll
  for (int r = 2; r < R; ++r) { t = cmulf(t, t1); v[r] = cmulf(v[r], t); }
}

__device__ __forceinline__ int rev3_5(int q) {
  int q5 = q / 5, q25 = q / 25;
  int d0 = q - 5 * q5, d1 = q5 - 5 * q25;
  return 25 * d0 + 5 * d1 + q25;
}

__device__ __forceinline__ int rev3_4(int q) {
  return ((q & 3) << 4) | (q & 12) | (q >> 4);
}

// ---------- single-butterfly DIF-625 stage (128 lanes/column, f1) ----------
template <int SUB, int SIGN>
__device__ __forceinline__ void dif5_stage_1b(float2* a, int idx) {
  int j = idx % SUB;
  int b = (idx / SUB) * (5 * SUB) + j;
  float2 u[5];
#pragma unroll
  for (int r = 0; r < 5; ++r) u[r] = a[b + SUB * r];
  bf5s<SIGN>(u);
  twchain<5>(u, cisf((float)SIGN * (TWO_PI / (float)(5 * SUB)) * (float)j));
#pragma unroll
  for (int r = 0; r < 5; ++r) a[b + SUB * r] = u[r];
}

// ---------- dual-butterfly DIF-625 stage, precomputed twiddles (i2) ----------
template <int SUB>
__device__ __forceinline__ void dif5_ip_stage_t(float2* a, int ln, float2 t1a, float2 t1b) {
  int i1 = ln, i2 = ln + 64;
  bool g2 = (i2 < 125);
  int j1 = i1 % SUB, j2 = i2 % SUB;
  int b1 = (i1 / SUB) * (5 * SUB) + j1;
  int b2 = (i2 / SUB) * (5 * SUB) + j2;
  float2 u[5], v[5];
#pragma unroll
  for (int r = 0; r < 5; ++r) u[r] = a[b1 + SUB * r];
  if (g2) {
#pragma unroll
    for (int r = 0; r < 5; ++r) v[r] = a[b2 + SUB * r];
  }
  bf5s<1>(u);
  twchain<5>(u, t1a);
  if (g2) {
    bf5s<1>(v);
    twchain<5>(v, t1b);
  }
#pragma unroll
  for (int r = 0; r < 5; ++r) a[b1 + SUB * r] = u[r];
  if (g2) {
#pragma unroll
    for (int r = 0; r < 5; ++r) a[b2 + SUB * r] = v[r];
  }
}

// ---------- DIF-256 stages 2-4 only, pad8-swizzled, hoisted twiddles (fi fwd) ----------
template <int SIGN>
__device__ __forceinline__ void dif256sw_s234(float2* a, int ln, float2 tw2, float2 tw3) {
  {
    int j = ln & 15, b = pad8(64 * (ln >> 4) + j);   // + 18*r exact
    float2 u[4];
#pragma unroll
    for (int r = 0; r < 4; ++r) u[r] = a[b + 18 * r];
    bf4s<SIGN>(u);
    twchain<4>(u, tw2);
#pragma unroll
    for (int r = 0; r < 4; ++r) a[b + 18 * r] = u[r];
  }
  {
    int j = ln & 3, jb = 16 * (ln >> 2) + j;
    float2 u[4];
#pragma unroll
    for (int r = 0; r < 4; ++r) u[r] = a[pad8(jb + 4 * r)];
    bf4s<SIGN>(u);
    twchain<4>(u, tw3);
#pragma unroll
    for (int r = 0; r < 4; ++r) a[pad8(jb + 4 * r)] = u[r];
  }
  {
    float2 u[4];
#pragma unroll
    for (int r = 0; r < 4; ++r) u[r] = a[pad8(4 * ln + r)];
    bf4s<SIGN>(u);
    int rv = rev3_4(ln);
#pragma unroll
    for (int r = 0; r < 4; ++r) a[pad8(64 * r + rv)] = u[r];
  }
}

// ---------- F1: float4 pack, 2 waves per 625-column, chained epilogue; zero E ----------
__global__ __launch_bounds__(512) void f1_kernel(const float* __restrict__ win,
                                                 const float* __restrict__ oin,
                                                 float2* __restrict__ G,
                                                 float* __restrict__ E) {
  __shared__ float2 A[4 * 625];    // 20 KB
  int blk = blockIdx.x;            // grid = BATCH * 64 = 512
  int tid = threadIdx.x;
  int gid = blk * 512 + tid;
  if (gid < 2 * BATCH * NB * NHOPS) E[gid] = 0.0f;   // replaces memset launch
  int sig = blk >> 6, g = blk & 63;
  int n1base = g * 4;
  const float4* wp4 = (const float4*)(win + (size_t)sig * L);
  const float4* op4 = (const float4*)(oin + (size_t)sig * L);
  for (int r = tid; r < 625; r += 512) {
    float4 wv = wp4[r * 64 + g];
    float4 ov = op4[r * 64 + g];
    A[0 * 625 + r] = make_float2(wv.x, ov.x);
    A[1 * 625 + r] = make_float2(wv.y, ov.y);
    A[2 * 625 + r] = make_float2(wv.z, ov.z);
    A[3 * 625 + r] = make_float2(wv.w, ov.w);
  }
  __syncthreads();
  // 2 waves per column: 128 lanes, 1 butterfly each (125 active)
  int col = tid >> 7, idx = tid & 127;
  float2* a = A + col * 625;
  bool act = (idx < 125);
  if (act) dif5_stage_1b<125, -1>(a, idx);
  __syncthreads();
  if (act) dif5_stage_1b<25, -1>(a, idx);
  __syncthreads();
  if (act) dif5_stage_1b<5, -1>(a, idx);
  __syncthreads();
  if (act) {
    float2 u[5];
#pragma unroll
    for (int r = 0; r < 5; ++r) u[r] = a[5 * idx + r];
    bf5s<-1>(u);
    int rv = rev3_5(idx);
#pragma unroll
    for (int r = 0; r < 5; ++r) a[125 * r + rv] = u[r];
  }
  __syncthreads();
  // chained epilogue over 512 threads: cc fixed, k2 steps by 128
  int cc = tid & 3, k20 = tid >> 2;   // k20 in [0,128)
  int n1 = n1base + cc;
  float w = -(TWO_PI / (float)L) * (float)n1;
  float2 t = cisf(w * (float)k20);
  float2 stp = cisf(w * 128.0f);
  for (int k2 = k20; k2 < 625; k2 += 128) {
    G[(size_t)sig * L + k2 * 256 + n1] = cmulf(A[cc * 625 + k2], t);
    t = cmulf(t, stp);
  }
}

// ---------- FI: fused f2+i1, 16 rows / 1024 thr / 2 bands per block (grid 1280).
//              Forward stage-1 in registers; aligned+spread (HP=656) H writes. ----------
__global__ __launch_bounds__(1024) void fi_kernel(const float2* __restrict__ G,
                                                  __half2* __restrict__ H) {
  __shared__ float2 Xb[16 * RS];   // forward spectra (pad8)
  __shared__ float2 Wb[16 * RS];   // inverse work (stages 1-3)
  int blk = blockIdx.x;            // grid = 4 * BATCH * 40 = 1280
  int bg  = blk / (BATCH * 40);    // band-group 0..3 (2 bands each)
  int rem = blk - bg * (BATCH * 40);
  int sig = rem / 40, gr = rem % 40;
  int k2base = gr * 16;
  int tid = threadIdx.x;
  int wv = tid >> 6, ln = tid & 63;
  int k2 = k2base + wv;
  bool act = (k2 < 625);
  float2* xr = Xb + wv * RS;
  float2* wr = Wb + wv * RS;

  // ---- hoisted stage twiddles (inverse sign; forward uses conj) ----
  float2 tw1 = cisf((TWO_PI / 256.0f) * (float)ln);
  float2 tw2 = cisf((TWO_PI / 64.0f) * (float)(ln & 15));
  float2 tw3 = cisf((TWO_PI / 16.0f) * (float)(ln & 3));

  // ---- forward DIF-256 of own row: stage 1 in registers (lane ln's G loads
  //      ARE its stage-1 inputs), stages 2-4 through LDS ----
  if (act) {
    const float2* Gr = G + (size_t)sig * L + k2 * 256;
    float2 x[4];
#pragma unroll
    for (int r = 0; r < 4; ++r) x[r] = Gr[ln + 64 * r];
    bf4s<-1>(x);
    twchain<4>(x, conjf(tw1));
    int b1w = pad8(ln);                           // + 72*r exact
#pragma unroll
    for (int r = 0; r < 4; ++r) xr[b1w + 72 * r] = x[r];
    dif256sw_s234<-1>(xr, ln, conjf(tw2), conjf(tw3));
  }

  // ---- hoisted per-lane LDS bases (stage strides are exact in pad8 space) ----
  int b1 = pad8(ln);                              // + 72*r
  int b2 = pad8(64 * (ln >> 4) + (ln & 15));      // + 18*r
  int jb3 = 16 * (ln >> 2) + (ln & 3);            // pad8(jb3 + 4*r)
  int kb = 625 * ln + k2;                         // + 40000*r  (bin number)

  // ---- fused stage-4 + epilogue constants ----
  int cc = tid & 15, q = tid >> 4;                // q in 0..63 (butterfly id)
  int rq = rev3_4(q);                             // n1 = 64*r + rq
  int k2e = k2base + cc;
  bool eact = (k2e < 625);
  float a0 = (TWO_PI / (float)L) * (float)k2e;
  float2 t0q = cisf(a0 * (float)rq);
  float2 stp = cisf(a0 * 64.0f);

#pragma unroll
  for (int bi = 0; bi < 2; ++bi) {
    int band = bg * 2 + bi;
    unsigned lo1, d1, lo2, d2;
    if (band < 7) {
      lo1 = 10000u * band + 1u;              d1 = 9999u;
      lo2 = (unsigned)L - 10000u * (band + 1); d2 = 9999u;
    } else {
      lo1 = 70001u; d1 = 19998u;             // 70001..89999
      lo2 = 0u;     d2 = 0u;                 // DC bin -> band 7
    }
    if (act) {
      float2 u[4];
      // stage 1: read Xb with in-register band mask, write Wb
#pragma unroll
      for (int r = 0; r < 4; ++r) {
        float2 x = xr[b1 + 72 * r];
        unsigned k = (unsigned)(kb + 40000 * r);
        bool in = ((k - lo1) <= d1) || ((k - lo2) <= d2);
        u[r] = in ? x : make_float2(0.0f, 0.0f);
      }
      bf4s<1>(u);
      twchain<4>(u, tw1);
#pragma unroll
      for (int r = 0; r < 4; ++r) wr[b1 + 72 * r] = u[r];
      // stage 2
#pragma unroll
      for (int r = 0; r < 4; ++r) u[r] = wr[b2 + 18 * r];
      bf4s<1>(u);
      twchain<4>(u, tw2);
#pragma unroll
      for (int r = 0; r < 4; ++r) wr[b2 + 18 * r] = u[r];
      // stage 3
#pragma unroll
      for (int r = 0; r < 4; ++r) u[r] = wr[pad8(jb3 + 4 * r)];
      bf4s<1>(u);
      twchain<4>(u, tw3);
#pragma unroll
      for (int r = 0; r < 4; ++r) wr[pad8(jb3 + 4 * r)] = u[r];
    }
    __syncthreads();
    // fused stage 4 + epilogue: butterfly q of row cc, outputs n1 = 64r + rq
    if (eact) {
      size_t obase = (size_t)(sig * NB + band) * HL;
      int b4 = cc * RS + pad8(4 * q);             // + r exact (r<4)
      float2 v[4];
#pragma unroll
      for (int r = 0; r < 4; ++r) v[r] = Wb[b4 + r];
      bf4s<1>(v);
      float2 t = t0q;
#pragma unroll
      for (int r = 0; r < 4; ++r) {
        int n1 = 64 * r + rq;
        float2 val = cmulf(v[r], t);
        H[obase + (size_t)n1 * HP + k2e] = __floats2half2_rn(val.x * INVL, val.y * INVL);
        t = cmulf(t, stp);
      }
    }
    __syncthreads();
  }
}

// ---------- I2: ONE column per wave, 4 columns / 256-thr block, grid 4096.
//              LDS exactly 20000 B -> 8 blocks/CU = 32 waves/CU, 2 exact
//              rounds. Energy in registers, partials spilled into dead A. ----------
__global__ __launch_bounds__(256, 8) void i2_kernel(const __half2* __restrict__ H,
                                                    float* __restrict__ E) {
  __shared__ float2 A[4 * 625];       // 20000 B (one column per wave)
  int blk = blockIdx.x;               // grid = BATCH*NB*64 = 4096
  int g = blk & 63, sb = blk >> 6;
  int band = sb & 7, sig = sb >> 3;
  int tid = threadIdx.x;
  int wv = tid >> 6, ln = tid & 63;
  size_t base = (size_t)(sig * NB + band) * HL;
  int n1 = 4 * g + wv;                // covers 0..255 across 64 blocks x 4 waves
  const __half2* Hc = H + base + (size_t)n1 * HP;
  int j1 = ln, j2 = ln + 64;
  bool g2 = (j2 < 125);
  __half2 h1[5], h2[5];
#pragma unroll
  for (int r = 0; r < 5; ++r) h1[r] = Hc[j1 + 125 * r];
  if (g2) {
#pragma unroll
    for (int r = 0; r < 5; ++r) h2[r] = Hc[j2 + 125 * r];
  }
  float2 tS1a = cisf((TWO_PI / 625.0f) * (float)j1);
  float2 tS1b = cisf((TWO_PI / 625.0f) * (float)j2);
  float2 tS2a = cisf((TWO_PI / 125.0f) * (float)(j1 % 25));
  float2 tS2b = cisf((TWO_PI / 125.0f) * (float)(j2 % 25));
  float2 tS3a = cisf((TWO_PI / 25.0f) * (float)(j1 % 5));
  float2 tS3b = cisf((TWO_PI / 25.0f) * (float)(j2 % 5));
  float2* a = A + wv * 625;

  // ---- stage 1 (from registers) ----
  {
    float2 u[5];
#pragma unroll
    for (int r = 0; r < 5; ++r) u[r] = __half22float2(h1[r]);
    bf5s<1>(u);
    twchain<5>(u, tS1a);
#pragma unroll
    for (int r = 0; r < 5; ++r) a[j1 + 125 * r] = u[r];
    if (g2) {
      float2 v[5];
#pragma unroll
      for (int r = 0; r < 5; ++r) v[r] = __half22float2(h2[r]);
      bf5s<1>(v);
      twchain<5>(v, tS1b);
#pragma unroll
      for (int r = 0; r < 5; ++r) a[j2 + 125 * r] = v[r];
    }
  }
  // ---- stages 2-3 ----
  dif5_ip_stage_t<25>(a, ln, tS2a, tS2b);
  dif5_ip_stage_t<5>(a, ln, tS3a, tS3b);
  // ---- final stage ----
  {
    float2 u[5], v[5];
#pragma unroll
    for (int r = 0; r < 5; ++r) u[r] = a[5 * j1 + r];
    if (g2) {
#pragma unroll
      for (int r = 0; r < 5; ++r) v[r] = a[5 * j2 + r];
    }
    bf5s<1>(u);
    if (g2) bf5s<1>(v);
    int rv1 = rev3_5(j1), rv2 = rev3_5(j2);
#pragma unroll
    for (int r = 0; r < 5; ++r) a[125 * r + rv1] = u[r];
    if (g2) {
#pragma unroll
      for (int r = 0; r < 5; ++r) a[125 * r + rv2] = v[r];
    }
  }
  // ---- energy pass into registers ----
  float ex[3] = {0.0f, 0.0f, 0.0f}, ey[3] = {0.0f, 0.0f, 0.0f};
#pragma unroll
  for (int k = 0; k < 3; ++k) {
    int h = ln + 64 * k;
    if (h < NHOPS) {
#pragma unroll
      for (int d = 0; d < 4; ++d) {
        float2 z = a[4 * h + d];
        ex[k] += z.x * z.x;
        ey[k] += z.y * z.y;
      }
    }
  }
  __syncthreads();                       // all waves done with A
  float* Ps = (float*)A;                 // 4 waves x 312 floats = 4992 B scratch
#pragma unroll
  for (int k = 0; k < 3; ++k) {
    int h = ln + 64 * k;
    if (h < NHOPS) {
      Ps[wv * (2 * NHOPS) + h] = ex[k];
      Ps[wv * (2 * NHOPS) + NHOPS + h] = ey[k];
    }
  }
  __syncthreads();
  int eb = (sig * NB + band) * NHOPS;
  for (int idx = tid; idx < 2 * NHOPS; idx += 256) {
    float v = Ps[idx] + Ps[2 * NHOPS + idx] + Ps[4 * NHOPS + idx] + Ps[6 * NHOPS + idx];
    int comp = idx / NHOPS, h = idx - comp * NHOPS;
    atomicAdd(&E[comp * (BATCH * NB * NHOPS) + eb + h], v);
  }
}

// ---------- finalize: loudness, diff, softmax (H pre-scaled by 1/L -> SC = 1/2048) ----------
__global__ __launch_bounds__(1024) void finalize_kernel(const float* __restrict__ E,
                                                        float* __restrict__ out) {
  constexpr int ND = BATCH * NB * NCHUNK;  // 9920
  constexpr float SC = 1.0f / 2048.0f;
  __shared__ float diffs[ND];
  __shared__ float sred[1024];
  int tid = threadIdx.x;
  for (int idx = tid; idx < ND; idx += 1024) {
    int sb = idx / NCHUNK;
    int k = idx - sb * NCHUNK;
    float msw = (E[sb * NHOPS + k] + E[sb * NHOPS + k + 1]) * SC;
    float mso = (E[64 * NHOPS + sb * NHOPS + k] + E[64 * NHOPS + sb * NHOPS + k + 1]) * SC;
    float lw = -0.691f + 10.0f * log10f(msw + 1e-12f);
    float lo = -0.691f + 10.0f * log10f(mso + 1e-12f);
    diffs[idx] = lw - lo;
  }
  __syncthreads();
  float mx = -3.4e38f;
  for (int idx = tid; idx < ND; idx += 1024) mx = fmaxf(mx, diffs[idx]);
  sred[tid] = mx;
  __syncthreads();
  for (int s = 512; s > 0; s >>= 1) {
    if (tid < s) sred[tid] = fmaxf(sred[tid], sred[tid + s]);
    __syncthreads();
  }
  float gmax = sred[0];
  __syncthreads();
  float se = 0.0f, swd = 0.0f;
  for (int idx = tid; idx < ND; idx += 1024) {
    float d = diffs[idx];
    float e = expf(d - gmax);
    se += e;
    swd += d * e;
  }
  sred[tid] = se; __syncthreads();
  for (int s = 512; s > 0; s >>= 1) { if (tid < s) sred[tid] += sred[tid + s]; __syncthreads(); }
  float tot = sred[0];
  __syncthreads();
  sred[tid] = swd; __syncthreads();
  for (int s = 512; s > 0; s >>= 1) { if (tid < s) sred[tid] += sred[tid + s]; __syncthreads(); }
  if (tid == 0) out[0] = sred[0] / tot;
}

extern "C" void kernel_launch(void* const* d_in, const int* in_sizes, int n_in,
                              void* d_out, int out_size, void* d_ws, size_t ws_size,
                              hipStream_t stream) {
  (void)in_sizes; (void)n_in; (void)out_size; (void)ws_size;
  char* ws = (char*)d_ws;
  float2*  G = (float2*)ws;                        // 10,240,000 B
  __half2* H = (__half2*)(ws + 10240000);          // 42,991,616 B (fp16, HP=656)
  float*   E = (float*)(ws + 53231616);            // 79,872 B [2][64][156]
  const float* w = (const float*)d_in[0];
  const float* o = (const float*)d_in[1];

  f1_kernel<<<dim3(BATCH * 64), dim3(512), 0, stream>>>(w, o, G, E);
  fi_kernel<<<dim3(4 * BATCH * 40), dim3(1024), 0, stream>>>(G, H);
  i2_kernel<<<dim3(BATCH * NB * 64), dim3(256), 0, stream>>>(H, E);
  finalize_kernel<<<dim3(1), dim3(1024), 0, stream>>>(E, (float*)d_out);
}